// Round 1
// baseline (366.248 us; speedup 1.0000x reference)
//
#include <hip/hip_runtime.h>

// LongTermMemoryMLP: 3 batched NT-GEMMs with per-batch weights.
//   h0 = relu(q  @ W0^T + b0)   [8,4096,512]x[8,1024,512]^T
//   h1 = relu(h0 @ W1^T + b1)   [8,4096,1024]x[8,1024,1024]^T
//   out =      h1 @ W2^T + b2   [8,4096,1024]x[8,512,1024]^T  (fp32 out)
// f16 MFMA, fp32 accumulate.
// Round 4: 256x256 tile, 8 waves, BK=32 with a 4-deep LDS ring (128 KiB) and
// COUNTED vmcnt at the K-tile boundary (vmcnt(8): two K-tiles of DMA stay in
// flight across the raw s_barrier; vmcnt(0) never appears in the main loop).
// This replaces the __syncthreads() full-drain that capped the old structure.

typedef _Float16 f16x8 __attribute__((ext_vector_type(8)));
typedef _Float16 f16x4 __attribute__((ext_vector_type(4)));
typedef float    f32x4 __attribute__((ext_vector_type(4)));

// async global->LDS DMA, 16B per lane; LDS dest = wave-uniform base + lane*16.
__device__ __forceinline__ void stage16(const void* g, void* l) {
    __builtin_amdgcn_global_load_lds(
        (const __attribute__((address_space(1))) unsigned int*)g,
        (__attribute__((address_space(3))) unsigned int*)l,
        16, 0, 0);
}

// ---- fp32 -> f16 casts, all four arrays in one launch ----
__device__ __forceinline__ void cast_seg(const float* __restrict__ s,
                                         _Float16* __restrict__ d, int n4) {
    const int stride = gridDim.x * 256;
    for (int i = blockIdx.x * 256 + threadIdx.x; i < n4; i += stride) {
        float4 f = reinterpret_cast<const float4*>(s)[i];
        f16x4 o;
        o[0] = (_Float16)f.x; o[1] = (_Float16)f.y;
        o[2] = (_Float16)f.z; o[3] = (_Float16)f.w;
        reinterpret_cast<f16x4*>(d)[i] = o;
    }
}

__global__ __launch_bounds__(256) void cast_all(
    const float* s0, _Float16* d0, int n0,
    const float* s1, _Float16* d1, int n1,
    const float* s2, _Float16* d2, int n2,
    const float* s3, _Float16* d3, int n3) {
    cast_seg(s0, d0, n0);
    cast_seg(s1, d1, n1);
    cast_seg(s2, d2, n2);
    cast_seg(s3, d3, n3);
}

// ---- deep-pipelined all-f16 GEMM: C[b,m,n] = sum_k A[b,m,k]*W[b,n,k] + bias
// 256x256 tile, BK=32, 8 waves (2Mx4N), each wave 8x4 x mfma_f32_16x16x32_f16.
// LDS ring of 4 K-tiles (4 x (8KB A + 8KB B) x2 halves... = 128 KiB total).
// One raw s_barrier per K-tile; counted vmcnt keeps 2 K-tiles of global->LDS
// DMA in flight across it.
template <bool RELU, bool OUT_F16>
__global__ __launch_bounds__(512, 2) void gemm_pipe(
    const _Float16* __restrict__ A, const _Float16* __restrict__ W,
    const float* __restrict__ bias, void* __restrict__ Outv,
    int M, int N, int K) {
    constexpr int BM = 256, BN = 256, BK = 32;
    constexpr int DEPTH = 4;                       // K-tiles resident in LDS
    __shared__ __align__(16) _Float16 As[DEPTH][BM * BK];   // 4 x 16 KiB
    __shared__ __align__(16) _Float16 Bs[DEPTH][BN * BK];   // 4 x 16 KiB

    const int tid  = threadIdx.x;
    const int lane = tid & 63;
    const int rowl = lane & 15;
    const int q8   = (lane >> 4) * 8;
    const int w    = tid >> 6;            // wave 0..7
    const int wm   = (w >> 2) * 128;      // 2 waves along M
    const int wn   = (w & 3) * 64;        // 4 waves along N

    const int bm = blockIdx.x, bn = blockIdx.y, b = blockIdx.z;

    // chunk c (0..1023, 8 f16 = 16 B each): source row c>>2, k (c&3)*8;
    // LDS dest f16-offset 8*c (contiguous lane*16B — DMA constraint).
    const int c0 = tid, c1 = tid + 512;
    const int ar0 = c0 >> 2, ak0 = (c0 & 3) * 8;
    const int ar1 = c1 >> 2, ak1 = (c1 & 3) * 8;

    const char* Ab = (const char*)(A + (size_t)b * M * K + (size_t)(bm * BM) * K);
    const char* Wb = (const char*)(W + (size_t)b * N * K + (size_t)(bn * BN) * K);
    size_t aoff0 = ((size_t)ar0 * K + ak0) * 2;
    size_t aoff1 = ((size_t)ar1 * K + ak1) * 2;
    size_t woff0 = ((size_t)ar0 * K + ak0) * 2;
    size_t woff1 = ((size_t)ar1 * K + ak1) * 2;
    constexpr size_t KSTEP = (size_t)BK * 2;      // byte advance per K-tile

    f32x4 acc[8][4];
#pragma unroll
    for (int mi = 0; mi < 8; ++mi)
#pragma unroll
        for (int ni = 0; ni < 4; ++ni)
            acc[mi][ni] = (f32x4){0.f, 0.f, 0.f, 0.f};

    const int nk = K / BK;

    // prologue: stage tiles 0..2 (12 DMA instrs/wave), wait until tile 0
    // has landed (allow the 8 loads of tiles 1,2 to stay in flight).
#pragma unroll
    for (int p = 0; p < DEPTH - 1; ++p) {
        if (p < nk) {
            stage16(Ab + aoff0, &As[p][8 * (size_t)c0]);
            stage16(Ab + aoff1, &As[p][8 * (size_t)c1]);
            stage16(Wb + woff0, &Bs[p][8 * (size_t)c0]);
            stage16(Wb + woff1, &Bs[p][8 * (size_t)c1]);
            aoff0 += KSTEP; aoff1 += KSTEP; woff0 += KSTEP; woff1 += KSTEP;
        }
    }
    asm volatile("s_waitcnt vmcnt(8)" ::: "memory");
    __builtin_amdgcn_s_barrier();

    for (int t = 0; t < nk; ++t) {
        const int cur = t & (DEPTH - 1);
        // issue next-next-next tile's DMA first: it has ~3 K-tile periods to land.
        if (t + 3 < nk) {
            const int nxt = (t + 3) & (DEPTH - 1);
            stage16(Ab + aoff0, &As[nxt][8 * (size_t)c0]);
            stage16(Ab + aoff1, &As[nxt][8 * (size_t)c1]);
            stage16(Wb + woff0, &Bs[nxt][8 * (size_t)c0]);
            stage16(Wb + woff1, &Bs[nxt][8 * (size_t)c1]);
            aoff0 += KSTEP; aoff1 += KSTEP; woff0 += KSTEP; woff1 += KSTEP;
        }

        f16x8 af[8], bf[4];
#pragma unroll
        for (int i = 0; i < 8; ++i)
            af[i] = *(const f16x8*)(&As[cur][(wm + i * 16 + rowl) * BK + q8]);
#pragma unroll
        for (int i = 0; i < 4; ++i)
            bf[i] = *(const f16x8*)(&Bs[cur][(wn + i * 16 + rowl) * BK + q8]);

        __builtin_amdgcn_s_setprio(1);
#pragma unroll
        for (int mi = 0; mi < 8; ++mi)
#pragma unroll
            for (int ni = 0; ni < 4; ++ni)
                acc[mi][ni] = __builtin_amdgcn_mfma_f32_16x16x32_f16(
                    af[mi], bf[ni], acc[mi][ni], 0, 0, 0);
        __builtin_amdgcn_s_setprio(0);

        // K-tile boundary: ensure tile t+1 has landed for THIS wave, then
        // barrier so it has landed for ALL waves. Counted wait: the most
        // recent 2 K-tiles (8 DMA instrs) may remain in flight.
        if (t + 1 < nk) {
            if (t + 3 < nk)
                asm volatile("s_waitcnt vmcnt(8)" ::: "memory");
            else if (t + 2 < nk)
                asm volatile("s_waitcnt vmcnt(4)" ::: "memory");
            else
                asm volatile("s_waitcnt vmcnt(0)" ::: "memory");
            __builtin_amdgcn_s_barrier();
        }
    }

    // epilogue: bias (+relu), store. C/D: col=lane&15, row=(lane>>4)*4+reg.
    const int q = lane >> 4;
    float bcol[4];
    {
        const float* bp = bias + (size_t)b * N + bn * BN + wn;
#pragma unroll
        for (int ni = 0; ni < 4; ++ni) bcol[ni] = bp[ni * 16 + rowl];
    }
#pragma unroll
    for (int mi = 0; mi < 8; ++mi) {
        const int row0 = bm * BM + wm + mi * 16 + q * 4;
#pragma unroll
        for (int r = 0; r < 4; ++r) {
            const size_t ro = (size_t)b * M * N + (size_t)(row0 + r) * N + bn * BN + wn;
#pragma unroll
            for (int ni = 0; ni < 4; ++ni) {
                float v = acc[mi][ni][r] + bcol[ni];
                if (RELU) v = fmaxf(v, 0.f);
                if (OUT_F16)
                    ((_Float16*)Outv)[ro + ni * 16 + rowl] = (_Float16)v;
                else
                    ((float*)Outv)[ro + ni * 16 + rowl] = v;
            }
        }
    }
}

// ---- legacy 2-barrier kernel, mixed f32/f16 operands (fallback path only) ----
__device__ __forceinline__ uint4 load8f32(const char* p) {
    const float4* fp = reinterpret_cast<const float4*>(p);
    float4 f0 = fp[0], f1 = fp[1];
    f16x8 o;
    o[0] = (_Float16)f0.x; o[1] = (_Float16)f0.y;
    o[2] = (_Float16)f0.z; o[3] = (_Float16)f0.w;
    o[4] = (_Float16)f1.x; o[5] = (_Float16)f1.y;
    o[6] = (_Float16)f1.z; o[7] = (_Float16)f1.w;
    return __builtin_bit_cast(uint4, o);
}

template <bool A_F16, bool W_F16, bool RELU, bool OUT_F16>
__global__ __launch_bounds__(256) void gemm_bias_act(
    const void* __restrict__ Av, const void* __restrict__ Wv,
    const float* __restrict__ bias, void* __restrict__ Outv,
    int M, int N, int K) {
    constexpr int BM = 128, BN = 128, BK = 32;
    __shared__ __align__(16) _Float16 As[BM * BK];
    __shared__ __align__(16) _Float16 Bs[BN * BK];

    const int tid  = threadIdx.x;
    const int lane = tid & 63;
    const int rowl = lane & 15;
    const int q8   = (lane >> 4) * 8;
    const int wm   = ((tid >> 6) >> 1) * 64;
    const int wn   = ((tid >> 6) & 1) * 64;
    const int bm = blockIdx.x, bn = blockIdx.y, b = blockIdx.z;

    const int c0 = tid, c1 = tid + 256;
    const int ar0 = c0 >> 2, ak0 = (c0 & 3) * 8;
    const int ar1 = c1 >> 2, ak1 = (c1 & 3) * 8;

    constexpr size_t esA = A_F16 ? 2 : 4;
    constexpr size_t esW = W_F16 ? 2 : 4;
    const char* Abase = (const char*)Av;
    const char* Wbase = (const char*)Wv;

    size_t aoff0 = ((size_t)b * M * K + (size_t)(bm * BM + ar0) * K + ak0) * esA;
    size_t aoff1 = ((size_t)b * M * K + (size_t)(bm * BM + ar1) * K + ak1) * esA;
    size_t woff0 = ((size_t)b * N * K + (size_t)(bn * BN + ar0) * K + ak0) * esW;
    size_t woff1 = ((size_t)b * N * K + (size_t)(bn * BN + ar1) * K + ak1) * esW;

    f32x4 acc[4][4];
#pragma unroll
    for (int mi = 0; mi < 4; ++mi)
#pragma unroll
        for (int ni = 0; ni < 4; ++ni)
            acc[mi][ni] = (f32x4){0.f, 0.f, 0.f, 0.f};

    const int nk = K / BK;
    for (int kk = 0; kk < nk; ++kk) {
        uint4 va0, va1, vw0, vw1;
        if (!A_F16) { va0 = load8f32(Abase + aoff0); va1 = load8f32(Abase + aoff1); }
        if (!W_F16) { vw0 = load8f32(Wbase + woff0); vw1 = load8f32(Wbase + woff1); }
        __syncthreads();
        if (A_F16) {
            stage16(Abase + aoff0, As + 8 * (size_t)c0);
            stage16(Abase + aoff1, As + 8 * (size_t)c1);
        } else {
            *(uint4*)(As + ar0 * BK + ak0) = va0;
            *(uint4*)(As + ar1 * BK + ak1) = va1;
        }
        if (W_F16) {
            stage16(Wbase + woff0, Bs + 8 * (size_t)c0);
            stage16(Wbase + woff1, Bs + 8 * (size_t)c1);
        } else {
            *(uint4*)(Bs + ar0 * BK + ak0) = vw0;
            *(uint4*)(Bs + ar1 * BK + ak1) = vw1;
        }
        aoff0 += BK * esA; aoff1 += BK * esA;
        woff0 += BK * esW; woff1 += BK * esW;
        __syncthreads();

        f16x8 af[4], bf[4];
#pragma unroll
        for (int i = 0; i < 4; ++i)
            af[i] = *(const f16x8*)(As + (wm + i * 16 + rowl) * BK + q8);
#pragma unroll
        for (int i = 0; i < 4; ++i)
            bf[i] = *(const f16x8*)(Bs + (wn + i * 16 + rowl) * BK + q8);
#pragma unroll
        for (int mi = 0; mi < 4; ++mi)
#pragma unroll
            for (int ni = 0; ni < 4; ++ni)
                acc[mi][ni] = __builtin_amdgcn_mfma_f32_16x16x32_f16(
                    af[mi], bf[ni], acc[mi][ni], 0, 0, 0);
    }

    const int q = lane >> 4;
    float bcol[4];
    {
        const float* bp = bias + (size_t)b * N + bn * BN + wn;
#pragma unroll
        for (int ni = 0; ni < 4; ++ni) bcol[ni] = bp[ni * 16 + rowl];
    }
#pragma unroll
    for (int mi = 0; mi < 4; ++mi) {
        const int row0 = bm * BM + wm + mi * 16 + q * 4;
#pragma unroll
        for (int r = 0; r < 4; ++r) {
            const size_t ro = (size_t)b * M * N + (size_t)(row0 + r) * N + bn * BN + wn;
#pragma unroll
            for (int ni = 0; ni < 4; ++ni) {
                float v = acc[mi][ni][r] + bcol[ni];
                if (RELU) v = fmaxf(v, 0.f);
                if (OUT_F16)
                    ((_Float16*)Outv)[ro + ni * 16 + rowl] = (_Float16)v;
                else
                    ((float*)Outv)[ro + ni * 16 + rowl] = v;
            }
        }
    }
}

extern "C" void kernel_launch(void* const* d_in, const int* in_sizes, int n_in,
                              void* d_out, int out_size, void* d_ws, size_t ws_size,
                              hipStream_t stream) {
    const int B = 8, S = 4096, DI = 512, DH = 1024, DO = 512;
    const float* query = (const float*)d_in[0];
    const float* W0    = (const float*)d_in[1];
    const float* b0    = (const float*)d_in[2];
    const float* W1    = (const float*)d_in[3];
    const float* b1    = (const float*)d_in[4];
    const float* W2    = (const float*)d_in[5];
    const float* b2    = (const float*)d_in[6];

    char* ws = (char*)d_ws;
    const size_t nH  = (size_t)B * S * DH;   // 33.5M
    const size_t nQ  = (size_t)B * S * DI;   // 16.8M
    const size_t nW0 = (size_t)B * DH * DI;  // 4.2M
    const size_t nW1 = (size_t)B * DH * DH;  // 8.4M
    const size_t nW2 = (size_t)B * DO * DH;  // 4.2M

    _Float16* h0 = (_Float16*)ws;             // 64 MiB
    _Float16* h1 = (_Float16*)(ws + nH * 2);  // 64 MiB
    const size_t off_casts = nH * 4;
    const size_t full_need = off_casts + (nQ + nW0 + nW1 + nW2) * 2;  // 192 MiB

    if (ws_size >= full_need) {
        _Float16* qf  = (_Float16*)(ws + off_casts);
        _Float16* w0f = qf + nQ;
        _Float16* w1f = w0f + nW0;
        _Float16* w2f = w1f + nW1;
        cast_all<<<dim3(2048), dim3(256), 0, stream>>>(
            query, qf, (int)(nQ / 4), W0, w0f, (int)(nW0 / 4),
            W1, w1f, (int)(nW1 / 4), W2, w2f, (int)(nW2 / 4));
        const dim3 blk(512);
        const dim3 g0(S / 256, DH / 256, B);
        const dim3 g2(S / 256, DO / 256, B);
        gemm_pipe<true,  true ><<<g0, blk, 0, stream>>>(qf, w0f, b0, h0, S, DH, DI);
        gemm_pipe<true,  true ><<<g0, blk, 0, stream>>>(h0, w1f, b1, h1, S, DH, DH);
        gemm_pipe<false, false><<<g2, blk, 0, stream>>>(h1, w2f, b2, d_out, S, DO, DH);
    } else {
        const dim3 blk(256);
        const dim3 g0(S / 128, DH / 128, B);
        const dim3 g2(S / 128, DO / 128, B);
        gemm_bias_act<false, false, true,  true ><<<g0, blk, 0, stream>>>(query, W0, b0, h0, S, DH, DI);
        gemm_bias_act<true,  false, true,  true ><<<g0, blk, 0, stream>>>(h0, W1, b1, h1, S, DH, DH);
        gemm_bias_act<true,  false, false, false><<<g2, blk, 0, stream>>>(h1, W2, b2, d_out, S, DO, DH);
    }
}

// Round 2
// 337.760 us; speedup vs baseline: 1.0843x; 1.0843x over previous
//
#include <hip/hip_runtime.h>

// LongTermMemoryMLP: 3 batched NT-GEMMs with per-batch weights.
//   h0 = relu(q  @ W0^T + b0)   [8,4096,512]x[8,1024,512]^T
//   h1 = relu(h0 @ W1^T + b1)   [8,4096,1024]x[8,1024,1024]^T
//   out =      h1 @ W2^T + b2   [8,4096,1024]x[8,512,1024]^T  (fp32 out)
// f16 MFMA, fp32 accumulate.
// Round 5: 8-phase interleaved schedule (T3+T4) on the 256x256/BK=32/ring-4
// geometry + LDS XOR swizzle (T2, both-sides: swizzled global source for the
// linear global_load_lds dest, same XOR on the ds_read address).
// Per iteration = 2 K-tiles, 8 phases; each phase: {ds_read subtile | 1 stage |
// barrier | setprio(1) 8xMFMA setprio(0) | barrier}. vmcnt(8) only at phase
// 4/8 boundaries; exact 8->4->0 drain at the tail.

typedef _Float16 f16x8 __attribute__((ext_vector_type(8)));
typedef _Float16 f16x4 __attribute__((ext_vector_type(4)));
typedef float    f32x4 __attribute__((ext_vector_type(4)));

// async global->LDS DMA, 16B per lane; LDS dest = wave-uniform base + lane*16.
__device__ __forceinline__ void stage16(const void* g, void* l) {
    __builtin_amdgcn_global_load_lds(
        (const __attribute__((address_space(1))) unsigned int*)g,
        (__attribute__((address_space(3))) unsigned int*)l,
        16, 0, 0);
}

template <int CNT> __device__ __forceinline__ void vmwait() {
    if constexpr (CNT == 8)      asm volatile("s_waitcnt vmcnt(8)" ::: "memory");
    else if constexpr (CNT == 4) asm volatile("s_waitcnt vmcnt(4)" ::: "memory");
    else                         asm volatile("s_waitcnt vmcnt(0)" ::: "memory");
}
__device__ __forceinline__ void barrier_() {
    asm volatile("s_barrier" ::: "memory");
}

// ---- fp32 -> f16 casts, all four arrays in one launch ----
__device__ __forceinline__ void cast_seg(const float* __restrict__ s,
                                         _Float16* __restrict__ d, int n4) {
    const int stride = gridDim.x * 256;
    for (int i = blockIdx.x * 256 + threadIdx.x; i < n4; i += stride) {
        float4 f = reinterpret_cast<const float4*>(s)[i];
        f16x4 o;
        o[0] = (_Float16)f.x; o[1] = (_Float16)f.y;
        o[2] = (_Float16)f.z; o[3] = (_Float16)f.w;
        reinterpret_cast<f16x4*>(d)[i] = o;
    }
}

__global__ __launch_bounds__(256) void cast_all(
    const float* s0, _Float16* d0, int n0,
    const float* s1, _Float16* d1, int n1,
    const float* s2, _Float16* d2, int n2,
    const float* s3, _Float16* d3, int n3) {
    cast_seg(s0, d0, n0);
    cast_seg(s1, d1, n1);
    cast_seg(s2, d2, n2);
    cast_seg(s3, d3, n3);
}

// ---- 8-phase pipelined all-f16 GEMM: C[b,m,n] = sum_k A[b,m,k]*W[b,n,k]+bias
// 256x256 tile, BK=32, 8 waves (2Mx4N), each wave 8x4 x mfma_f32_16x16x32_f16.
// LDS ring of 4 K-tiles (128 KiB). LDS layout: row-major [256][32] f16 per
// tile, but the 16B k-chunk within each row is XOR-swizzled by (row>>1)&3 —
// applied on the global SOURCE address (DMA dest stays linear) and on the
// ds_read address (same involution) -> conflict-free b128 reads.
template <bool RELU, bool OUT_F16>
__global__ __launch_bounds__(512, 2) void gemm_pipe8(
    const _Float16* __restrict__ A, const _Float16* __restrict__ W,
    const float* __restrict__ bias, void* __restrict__ Outv,
    int M, int N, int K) {
    constexpr int BM = 256, BN = 256, BK = 32;
    constexpr int DEPTH = 4;                       // K-tiles resident in LDS
    __shared__ __align__(16) _Float16 As[DEPTH][BM * BK];   // 4 x 16 KiB
    __shared__ __align__(16) _Float16 Bs[DEPTH][BN * BK];   // 4 x 16 KiB

    const int tid  = threadIdx.x;
    const int lane = tid & 63;
    const int rowl = lane & 15;
    // swizzled k-chunk for fragment reads: q' = (lane>>4) ^ ((row>>1)&3);
    // row = 16*m + rowl  =>  (row>>1)&3 == (rowl>>1)&3  (per-thread constant).
    const int qswz = (((lane >> 4) ^ ((rowl >> 1) & 3)) * 8);
    const int w    = tid >> 6;            // wave 0..7
    const int wm   = (w >> 2) * 128;      // 2 waves along M
    const int wn   = (w & 3) * 64;        // 4 waves along N

    const int bm = blockIdx.x, bn = blockIdx.y, b = blockIdx.z;

    // chunk c (0..1023, 8 f16 = 16 B each): LDS dest f16-offset 8*c (linear —
    // DMA constraint); holds global (row=c>>2, k-chunk (c&3)^((row>>1)&3)).
    const int c0 = tid, c1 = tid + 512;
    const int ar0 = c0 >> 2, ar1 = c1 >> 2;
    const int ak0 = (((c0 & 3) ^ ((ar0 >> 1) & 3)) * 8);
    const int ak1 = (((c1 & 3) ^ ((ar1 >> 1) & 3)) * 8);

    const char* Ab = (const char*)(A + (size_t)b * M * K + (size_t)(bm * BM) * K);
    const char* Wb = (const char*)(W + (size_t)b * N * K + (size_t)(bn * BN) * K);
    size_t aoff0 = ((size_t)ar0 * K + ak0) * 2;
    size_t aoff1 = ((size_t)ar1 * K + ak1) * 2;
    size_t woff0 = ((size_t)ar0 * K + ak0) * 2;
    size_t woff1 = ((size_t)ar1 * K + ak1) * 2;
    constexpr size_t KSTEP = (size_t)BK * 2;      // byte advance per K-tile

    f32x4 acc[8][4];
#pragma unroll
    for (int mi = 0; mi < 8; ++mi)
#pragma unroll
        for (int ni = 0; ni < 4; ++ni)
            acc[mi][ni] = (f32x4){0.f, 0.f, 0.f, 0.f};

    const int nk = K / BK;          // even, >= 6 (K in {512,1024})
    const int niter = nk / 2;

    // prologue: stage tiles 0..2 (12 DMA instrs/wave); allow tiles 1,2
    // (8 instrs) in flight, tile 0 landed.
#pragma unroll
    for (int p = 0; p < DEPTH - 1; ++p) {
        stage16(Ab + aoff0, &As[p][8 * (size_t)c0]);
        stage16(Ab + aoff1, &As[p][8 * (size_t)c1]);
        stage16(Wb + woff0, &Bs[p][8 * (size_t)c0]);
        stage16(Wb + woff1, &Bs[p][8 * (size_t)c1]);
        aoff0 += KSTEP; aoff1 += KSTEP; woff0 += KSTEP; woff1 += KSTEP;
    }
    vmwait<8>();
    barrier_();

#define BFLOAD(SS)                                                            \
    bf[0] = *(const f16x8*)(&Bs[SS][(wn +  0 + rowl) * BK + qswz]);           \
    bf[1] = *(const f16x8*)(&Bs[SS][(wn + 16 + rowl) * BK + qswz]);           \
    bf[2] = *(const f16x8*)(&Bs[SS][(wn + 32 + rowl) * BK + qswz]);           \
    bf[3] = *(const f16x8*)(&Bs[SS][(wn + 48 + rowl) * BK + qswz]);

#define LDA2(SS, MI)                                                          \
    f16x8 a0 = *(const f16x8*)(&As[SS][(wm + (MI)*16 + rowl) * BK + qswz]);   \
    f16x8 a1 = *(const f16x8*)(&As[SS][(wm + (MI)*16 + 16 + rowl) * BK + qswz]);

#define MFMA8(MI)                                                             \
    __builtin_amdgcn_s_setprio(1);                                            \
    acc[MI][0]   = __builtin_amdgcn_mfma_f32_16x16x32_f16(a0, bf[0], acc[MI][0],   0, 0, 0); \
    acc[MI][1]   = __builtin_amdgcn_mfma_f32_16x16x32_f16(a0, bf[1], acc[MI][1],   0, 0, 0); \
    acc[MI][2]   = __builtin_amdgcn_mfma_f32_16x16x32_f16(a0, bf[2], acc[MI][2],   0, 0, 0); \
    acc[MI][3]   = __builtin_amdgcn_mfma_f32_16x16x32_f16(a0, bf[3], acc[MI][3],   0, 0, 0); \
    acc[MI+1][0] = __builtin_amdgcn_mfma_f32_16x16x32_f16(a1, bf[0], acc[MI+1][0], 0, 0, 0); \
    acc[MI+1][1] = __builtin_amdgcn_mfma_f32_16x16x32_f16(a1, bf[1], acc[MI+1][1], 0, 0, 0); \
    acc[MI+1][2] = __builtin_amdgcn_mfma_f32_16x16x32_f16(a1, bf[2], acc[MI+1][2], 0, 0, 0); \
    acc[MI+1][3] = __builtin_amdgcn_mfma_f32_16x16x32_f16(a1, bf[3], acc[MI+1][3], 0, 0, 0); \
    __builtin_amdgcn_s_setprio(0);

    for (int i = 0; i < niter; ++i) {
        const int t0 = 2 * i;
        const int s0 = t0 & 3, s1 = (t0 + 1) & 3;
        const int sA = (t0 + 3) & 3;     // stage target, phases 0-3 (tile t0+3)
        const int sB = s0;               // stage target, phases 4-7 (tile t0+4)
        const bool stg03 = (t0 + 3 < nk);
        const bool stg47 = (t0 + 4 < nk);

        f16x8 bf[4];

        // ---- phase 0: tile t0, mi 0-1 ----
        {
            BFLOAD(s0);
            LDA2(s0, 0);
            if (stg03) stage16(Ab + aoff0, &As[sA][8 * (size_t)c0]);
            barrier_();
            MFMA8(0);
            barrier_();
        }
        // ---- phase 1: tile t0, mi 2-3 ----
        {
            LDA2(s0, 2);
            if (stg03) stage16(Ab + aoff1, &As[sA][8 * (size_t)c1]);
            barrier_();
            MFMA8(2);
            barrier_();
        }
        // ---- phase 2: tile t0, mi 4-5 ----
        {
            LDA2(s0, 4);
            if (stg03) stage16(Wb + woff0, &Bs[sA][8 * (size_t)c0]);
            barrier_();
            MFMA8(4);
            barrier_();
        }
        // ---- phase 3: tile t0, mi 6-7; K-tile boundary wait ----
        {
            LDA2(s0, 6);
            if (stg03) stage16(Wb + woff1, &Bs[sA][8 * (size_t)c1]);
            barrier_();
            MFMA8(6);
            // tile t0+1 must be landed for all waves after this barrier.
            if (i + 1 < niter) vmwait<8>(); else vmwait<0>();
            barrier_();
        }
        aoff0 += KSTEP; aoff1 += KSTEP; woff0 += KSTEP; woff1 += KSTEP;

        // ---- phase 4: tile t0+1, mi 0-1 ----
        {
            BFLOAD(s1);
            LDA2(s1, 0);
            if (stg47) stage16(Ab + aoff0, &As[sB][8 * (size_t)c0]);
            barrier_();
            MFMA8(0);
            barrier_();
        }
        // ---- phase 5: tile t0+1, mi 2-3 ----
        {
            LDA2(s1, 2);
            if (stg47) stage16(Ab + aoff1, &As[sB][8 * (size_t)c1]);
            barrier_();
            MFMA8(2);
            barrier_();
        }
        // ---- phase 6: tile t0+1, mi 4-5 ----
        {
            LDA2(s1, 4);
            if (stg47) stage16(Wb + woff0, &Bs[sB][8 * (size_t)c0]);
            barrier_();
            MFMA8(4);
            barrier_();
        }
        // ---- phase 7: tile t0+1, mi 6-7; iteration boundary wait ----
        {
            LDA2(s1, 6);
            if (stg47) stage16(Wb + woff1, &Bs[sB][8 * (size_t)c1]);
            barrier_();
            MFMA8(6);
            // tile t0+2 must be landed for all waves after this barrier.
            if (i + 2 < niter)      vmwait<8>();
            else if (i + 1 < niter) vmwait<4>();
            barrier_();
        }
        aoff0 += KSTEP; aoff1 += KSTEP; woff0 += KSTEP; woff1 += KSTEP;
    }
#undef BFLOAD
#undef LDA2
#undef MFMA8

    // epilogue: bias (+relu), store. C/D: col=lane&15, row=(lane>>4)*4+reg.
    const int q = lane >> 4;
    float bcol[4];
    {
        const float* bp = bias + (size_t)b * N + bn * BN + wn;
#pragma unroll
        for (int ni = 0; ni < 4; ++ni) bcol[ni] = bp[ni * 16 + rowl];
    }
#pragma unroll
    for (int mi = 0; mi < 8; ++mi) {
        const int row0 = bm * BM + wm + mi * 16 + q * 4;
#pragma unroll
        for (int r = 0; r < 4; ++r) {
            const size_t ro = (size_t)b * M * N + (size_t)(row0 + r) * N + bn * BN + wn;
#pragma unroll
            for (int ni = 0; ni < 4; ++ni) {
                float v = acc[mi][ni][r] + bcol[ni];
                if (RELU) v = fmaxf(v, 0.f);
                if (OUT_F16)
                    ((_Float16*)Outv)[ro + ni * 16 + rowl] = (_Float16)v;
                else
                    ((float*)Outv)[ro + ni * 16 + rowl] = v;
            }
        }
    }
}

// ---- legacy 2-barrier kernel, mixed f32/f16 operands (fallback path only) ----
__device__ __forceinline__ uint4 load8f32(const char* p) {
    const float4* fp = reinterpret_cast<const float4*>(p);
    float4 f0 = fp[0], f1 = fp[1];
    f16x8 o;
    o[0] = (_Float16)f0.x; o[1] = (_Float16)f0.y;
    o[2] = (_Float16)f0.z; o[3] = (_Float16)f0.w;
    o[4] = (_Float16)f1.x; o[5] = (_Float16)f1.y;
    o[6] = (_Float16)f1.z; o[7] = (_Float16)f1.w;
    return __builtin_bit_cast(uint4, o);
}

template <bool A_F16, bool W_F16, bool RELU, bool OUT_F16>
__global__ __launch_bounds__(256) void gemm_bias_act(
    const void* __restrict__ Av, const void* __restrict__ Wv,
    const float* __restrict__ bias, void* __restrict__ Outv,
    int M, int N, int K) {
    constexpr int BM = 128, BN = 128, BK = 32;
    __shared__ __align__(16) _Float16 As[BM * BK];
    __shared__ __align__(16) _Float16 Bs[BN * BK];

    const int tid  = threadIdx.x;
    const int lane = tid & 63;
    const int rowl = lane & 15;
    const int q8   = (lane >> 4) * 8;
    const int wm   = ((tid >> 6) >> 1) * 64;
    const int wn   = ((tid >> 6) & 1) * 64;
    const int bm = blockIdx.x, bn = blockIdx.y, b = blockIdx.z;

    const int c0 = tid, c1 = tid + 256;
    const int ar0 = c0 >> 2, ak0 = (c0 & 3) * 8;
    const int ar1 = c1 >> 2, ak1 = (c1 & 3) * 8;

    constexpr size_t esA = A_F16 ? 2 : 4;
    constexpr size_t esW = W_F16 ? 2 : 4;
    const char* Abase = (const char*)Av;
    const char* Wbase = (const char*)Wv;

    size_t aoff0 = ((size_t)b * M * K + (size_t)(bm * BM + ar0) * K + ak0) * esA;
    size_t aoff1 = ((size_t)b * M * K + (size_t)(bm * BM + ar1) * K + ak1) * esA;
    size_t woff0 = ((size_t)b * N * K + (size_t)(bn * BN + ar0) * K + ak0) * esW;
    size_t woff1 = ((size_t)b * N * K + (size_t)(bn * BN + ar1) * K + ak1) * esW;

    f32x4 acc[4][4];
#pragma unroll
    for (int mi = 0; mi < 4; ++mi)
#pragma unroll
        for (int ni = 0; ni < 4; ++ni)
            acc[mi][ni] = (f32x4){0.f, 0.f, 0.f, 0.f};

    const int nk = K / BK;
    for (int kk = 0; kk < nk; ++kk) {
        uint4 va0, va1, vw0, vw1;
        if (!A_F16) { va0 = load8f32(Abase + aoff0); va1 = load8f32(Abase + aoff1); }
        if (!W_F16) { vw0 = load8f32(Wbase + woff0); vw1 = load8f32(Wbase + woff1); }
        __syncthreads();
        if (A_F16) {
            stage16(Abase + aoff0, As + 8 * (size_t)c0);
            stage16(Abase + aoff1, As + 8 * (size_t)c1);
        } else {
            *(uint4*)(As + ar0 * BK + ak0) = va0;
            *(uint4*)(As + ar1 * BK + ak1) = va1;
        }
        if (W_F16) {
            stage16(Wbase + woff0, Bs + 8 * (size_t)c0);
            stage16(Wbase + woff1, Bs + 8 * (size_t)c1);
        } else {
            *(uint4*)(Bs + ar0 * BK + ak0) = vw0;
            *(uint4*)(Bs + ar1 * BK + ak1) = vw1;
        }
        aoff0 += BK * esA; aoff1 += BK * esA;
        woff0 += BK * esW; woff1 += BK * esW;
        __syncthreads();

        f16x8 af[4], bf[4];
#pragma unroll
        for (int i = 0; i < 4; ++i)
            af[i] = *(const f16x8*)(As + (wm + i * 16 + rowl) * BK + q8);
#pragma unroll
        for (int i = 0; i < 4; ++i)
            bf[i] = *(const f16x8*)(Bs + (wn + i * 16 + rowl) * BK + q8);
#pragma unroll
        for (int mi = 0; mi < 4; ++mi)
#pragma unroll
            for (int ni = 0; ni < 4; ++ni)
                acc[mi][ni] = __builtin_amdgcn_mfma_f32_16x16x32_f16(
                    af[mi], bf[ni], acc[mi][ni], 0, 0, 0);
    }

    const int q = lane >> 4;
    float bcol[4];
    {
        const float* bp = bias + (size_t)b * N + bn * BN + wn;
#pragma unroll
        for (int ni = 0; ni < 4; ++ni) bcol[ni] = bp[ni * 16 + rowl];
    }
#pragma unroll
    for (int mi = 0; mi < 4; ++mi) {
        const int row0 = bm * BM + wm + mi * 16 + q * 4;
#pragma unroll
        for (int r = 0; r < 4; ++r) {
            const size_t ro = (size_t)b * M * N + (size_t)(row0 + r) * N + bn * BN + wn;
#pragma unroll
            for (int ni = 0; ni < 4; ++ni) {
                float v = acc[mi][ni][r] + bcol[ni];
                if (RELU) v = fmaxf(v, 0.f);
                if (OUT_F16)
                    ((_Float16*)Outv)[ro + ni * 16 + rowl] = (_Float16)v;
                else
                    ((float*)Outv)[ro + ni * 16 + rowl] = v;
            }
        }
    }
}

extern "C" void kernel_launch(void* const* d_in, const int* in_sizes, int n_in,
                              void* d_out, int out_size, void* d_ws, size_t ws_size,
                              hipStream_t stream) {
    const int B = 8, S = 4096, DI = 512, DH = 1024, DO = 512;
    const float* query = (const float*)d_in[0];
    const float* W0    = (const float*)d_in[1];
    const float* b0    = (const float*)d_in[2];
    const float* W1    = (const float*)d_in[3];
    const float* b1    = (const float*)d_in[4];
    const float* W2    = (const float*)d_in[5];
    const float* b2    = (const float*)d_in[6];

    char* ws = (char*)d_ws;
    const size_t nH  = (size_t)B * S * DH;   // 33.5M
    const size_t nQ  = (size_t)B * S * DI;   // 16.8M
    const size_t nW0 = (size_t)B * DH * DI;  // 4.2M
    const size_t nW1 = (size_t)B * DH * DH;  // 8.4M
    const size_t nW2 = (size_t)B * DO * DH;  // 4.2M

    _Float16* h0 = (_Float16*)ws;             // 64 MiB
    _Float16* h1 = (_Float16*)(ws + nH * 2);  // 64 MiB
    const size_t off_casts = nH * 4;
    const size_t full_need = off_casts + (nQ + nW0 + nW1 + nW2) * 2;  // 192 MiB

    if (ws_size >= full_need) {
        _Float16* qf  = (_Float16*)(ws + off_casts);
        _Float16* w0f = qf + nQ;
        _Float16* w1f = w0f + nW0;
        _Float16* w2f = w1f + nW1;
        cast_all<<<dim3(2048), dim3(256), 0, stream>>>(
            query, qf, (int)(nQ / 4), W0, w0f, (int)(nW0 / 4),
            W1, w1f, (int)(nW1 / 4), W2, w2f, (int)(nW2 / 4));
        const dim3 blk(512);
        const dim3 g0(S / 256, DH / 256, B);
        const dim3 g2(S / 256, DO / 256, B);
        gemm_pipe8<true,  true ><<<g0, blk, 0, stream>>>(qf, w0f, b0, h0, S, DH, DI);
        gemm_pipe8<true,  true ><<<g0, blk, 0, stream>>>(h0, w1f, b1, h1, S, DH, DH);
        gemm_pipe8<false, false><<<g2, blk, 0, stream>>>(h1, w2f, b2, d_out, S, DO, DH);
    } else {
        const dim3 blk(256);
        const dim3 g0(S / 128, DH / 128, B);
        const dim3 g2(S / 128, DO / 128, B);
        gemm_bias_act<false, false, true,  true ><<<g0, blk, 0, stream>>>(query, W0, b0, h0, S, DH, DI);
        gemm_bias_act<true,  false, true,  true ><<<g0, blk, 0, stream>>>(h0, W1, b1, h1, S, DH, DH);
        gemm_bias_act<true,  false, false, false><<<g2, blk, 0, stream>>>(h1, W2, b2, d_out, S, DO, DH);
    }
}

// Round 3
// 336.987 us; speedup vs baseline: 1.0868x; 1.0023x over previous
//
#include <hip/hip_runtime.h>

// LongTermMemoryMLP: 3 batched NT-GEMMs with per-batch weights.
//   h0 = relu(q  @ W0^T + b0)   [8,4096,512]x[8,1024,512]^T
//   h1 = relu(h0 @ W1^T + b1)   [8,4096,1024]x[8,1024,1024]^T
//   out =      h1 @ W2^T + b2   [8,4096,1024]x[8,512,1024]^T  (fp32 out)
// f16 MFMA, fp32 accumulate.
// Round 6: coarsen the interleave to the verified m201 granularity —
// 4 phases per 2 K-tiles, 16 MFMA per barrier-pair (was 8). Keeps the
// conflict-free XOR swizzle (R5: bank conflicts 6.29M -> 0) and the
// counted vmcnt(8) ring (never drains to 0 in steady state).

typedef _Float16 f16x8 __attribute__((ext_vector_type(8)));
typedef _Float16 f16x4 __attribute__((ext_vector_type(4)));
typedef float    f32x4 __attribute__((ext_vector_type(4)));

// async global->LDS DMA, 16B per lane; LDS dest = wave-uniform base + lane*16.
__device__ __forceinline__ void stage16(const void* g, void* l) {
    __builtin_amdgcn_global_load_lds(
        (const __attribute__((address_space(1))) unsigned int*)g,
        (__attribute__((address_space(3))) unsigned int*)l,
        16, 0, 0);
}

template <int CNT> __device__ __forceinline__ void vmwait() {
    if constexpr (CNT == 8)      asm volatile("s_waitcnt vmcnt(8)" ::: "memory");
    else if constexpr (CNT == 4) asm volatile("s_waitcnt vmcnt(4)" ::: "memory");
    else                         asm volatile("s_waitcnt vmcnt(0)" ::: "memory");
}
__device__ __forceinline__ void barrier_() {
    asm volatile("s_barrier" ::: "memory");
}

// ---- fp32 -> f16 casts, all four arrays in one launch ----
__device__ __forceinline__ void cast_seg(const float* __restrict__ s,
                                         _Float16* __restrict__ d, int n4) {
    const int stride = gridDim.x * 256;
    for (int i = blockIdx.x * 256 + threadIdx.x; i < n4; i += stride) {
        float4 f = reinterpret_cast<const float4*>(s)[i];
        f16x4 o;
        o[0] = (_Float16)f.x; o[1] = (_Float16)f.y;
        o[2] = (_Float16)f.z; o[3] = (_Float16)f.w;
        reinterpret_cast<f16x4*>(d)[i] = o;
    }
}

__global__ __launch_bounds__(256) void cast_all(
    const float* s0, _Float16* d0, int n0,
    const float* s1, _Float16* d1, int n1,
    const float* s2, _Float16* d2, int n2,
    const float* s3, _Float16* d3, int n3) {
    cast_seg(s0, d0, n0);
    cast_seg(s1, d1, n1);
    cast_seg(s2, d2, n2);
    cast_seg(s3, d3, n3);
}

// ---- 4-phase pipelined all-f16 GEMM: C[b,m,n] = sum_k A[b,m,k]*W[b,n,k]+bias
// 256x256 tile, BK=32, 8 waves (2Mx4N), each wave 8x4 x mfma_f32_16x16x32_f16.
// LDS ring of 4 K-tiles (128 KiB). Per iteration = 2 K-tiles, 4 phases:
//   phase: {4-8 x ds_read_b128 | 2 x stage16 | barrier | 16 MFMA | barrier}
// vmcnt(8) only at tile boundaries (phases 1/3); 8->4->0 drain at the tail.
// LDS 16B k-chunk XOR-swizzled by (row>>1)&3 on BOTH sides (global source for
// the linear DMA dest; same XOR on ds_read) -> conflict-free b128 reads.
template <bool RELU, bool OUT_F16>
__global__ __launch_bounds__(512, 2) void gemm_pipe4(
    const _Float16* __restrict__ A, const _Float16* __restrict__ W,
    const float* __restrict__ bias, void* __restrict__ Outv,
    int M, int N, int K) {
    constexpr int BM = 256, BN = 256, BK = 32;
    constexpr int DEPTH = 4;                       // K-tiles resident in LDS
    __shared__ __align__(16) _Float16 As[DEPTH][BM * BK];   // 4 x 16 KiB
    __shared__ __align__(16) _Float16 Bs[DEPTH][BN * BK];   // 4 x 16 KiB

    const int tid  = threadIdx.x;
    const int lane = tid & 63;
    const int rowl = lane & 15;
    // swizzled k-chunk for fragment reads: q' = (lane>>4) ^ ((row>>1)&3);
    // row = 16*m + rowl  =>  (row>>1)&3 == (rowl>>1)&3  (per-thread constant).
    const int qswz = (((lane >> 4) ^ ((rowl >> 1) & 3)) * 8);
    const int w    = tid >> 6;            // wave 0..7
    const int wm   = (w >> 2) * 128;      // 2 waves along M
    const int wn   = (w & 3) * 64;        // 4 waves along N

    const int bm = blockIdx.x, bn = blockIdx.y, b = blockIdx.z;

    // chunk c (0..1023, 8 f16 = 16 B each): LDS dest f16-offset 8*c (linear —
    // DMA constraint); holds global (row=c>>2, k-chunk (c&3)^((row>>1)&3)).
    const int c0 = tid, c1 = tid + 512;
    const int ar0 = c0 >> 2, ar1 = c1 >> 2;
    const int ak0 = (((c0 & 3) ^ ((ar0 >> 1) & 3)) * 8);
    const int ak1 = (((c1 & 3) ^ ((ar1 >> 1) & 3)) * 8);

    const char* Ab = (const char*)(A + (size_t)b * M * K + (size_t)(bm * BM) * K);
    const char* Wb = (const char*)(W + (size_t)b * N * K + (size_t)(bn * BN) * K);
    size_t aoff0 = ((size_t)ar0 * K + ak0) * 2;
    size_t aoff1 = ((size_t)ar1 * K + ak1) * 2;
    size_t woff0 = ((size_t)ar0 * K + ak0) * 2;
    size_t woff1 = ((size_t)ar1 * K + ak1) * 2;
    constexpr size_t KSTEP = (size_t)BK * 2;      // byte advance per K-tile

    f32x4 acc[8][4];
#pragma unroll
    for (int mi = 0; mi < 8; ++mi)
#pragma unroll
        for (int ni = 0; ni < 4; ++ni)
            acc[mi][ni] = (f32x4){0.f, 0.f, 0.f, 0.f};

    const int nk = K / BK;          // even, >= 6 (K in {512,1024})
    const int niter = nk / 2;

    // prologue: stage tiles 0..2 (12 DMA instrs/wave); allow tiles 1,2
    // (8 instrs) in flight, tile 0 landed.
#pragma unroll
    for (int p = 0; p < DEPTH - 1; ++p) {
        stage16(Ab + aoff0, &As[p][8 * (size_t)c0]);
        stage16(Ab + aoff1, &As[p][8 * (size_t)c1]);
        stage16(Wb + woff0, &Bs[p][8 * (size_t)c0]);
        stage16(Wb + woff1, &Bs[p][8 * (size_t)c1]);
        aoff0 += KSTEP; aoff1 += KSTEP; woff0 += KSTEP; woff1 += KSTEP;
    }
    vmwait<8>();
    barrier_();

#define BFLOAD(SS)                                                            \
    bf[0] = *(const f16x8*)(&Bs[SS][(wn +  0 + rowl) * BK + qswz]);           \
    bf[1] = *(const f16x8*)(&Bs[SS][(wn + 16 + rowl) * BK + qswz]);           \
    bf[2] = *(const f16x8*)(&Bs[SS][(wn + 32 + rowl) * BK + qswz]);           \
    bf[3] = *(const f16x8*)(&Bs[SS][(wn + 48 + rowl) * BK + qswz]);

#define LDA4(SS, M0)                                                          \
    af[0] = *(const f16x8*)(&As[SS][(wm + ((M0)+0)*16 + rowl) * BK + qswz]);  \
    af[1] = *(const f16x8*)(&As[SS][(wm + ((M0)+1)*16 + rowl) * BK + qswz]);  \
    af[2] = *(const f16x8*)(&As[SS][(wm + ((M0)+2)*16 + rowl) * BK + qswz]);  \
    af[3] = *(const f16x8*)(&As[SS][(wm + ((M0)+3)*16 + rowl) * BK + qswz]);

#define MFMA16(M0)                                                            \
    __builtin_amdgcn_s_setprio(1);                                            \
    acc[(M0)+0][0] = __builtin_amdgcn_mfma_f32_16x16x32_f16(af[0], bf[0], acc[(M0)+0][0], 0, 0, 0); \
    acc[(M0)+0][1] = __builtin_amdgcn_mfma_f32_16x16x32_f16(af[0], bf[1], acc[(M0)+0][1], 0, 0, 0); \
    acc[(M0)+0][2] = __builtin_amdgcn_mfma_f32_16x16x32_f16(af[0], bf[2], acc[(M0)+0][2], 0, 0, 0); \
    acc[(M0)+0][3] = __builtin_amdgcn_mfma_f32_16x16x32_f16(af[0], bf[3], acc[(M0)+0][3], 0, 0, 0); \
    acc[(M0)+1][0] = __builtin_amdgcn_mfma_f32_16x16x32_f16(af[1], bf[0], acc[(M0)+1][0], 0, 0, 0); \
    acc[(M0)+1][1] = __builtin_amdgcn_mfma_f32_16x16x32_f16(af[1], bf[1], acc[(M0)+1][1], 0, 0, 0); \
    acc[(M0)+1][2] = __builtin_amdgcn_mfma_f32_16x16x32_f16(af[1], bf[2], acc[(M0)+1][2], 0, 0, 0); \
    acc[(M0)+1][3] = __builtin_amdgcn_mfma_f32_16x16x32_f16(af[1], bf[3], acc[(M0)+1][3], 0, 0, 0); \
    acc[(M0)+2][0] = __builtin_amdgcn_mfma_f32_16x16x32_f16(af[2], bf[0], acc[(M0)+2][0], 0, 0, 0); \
    acc[(M0)+2][1] = __builtin_amdgcn_mfma_f32_16x16x32_f16(af[2], bf[1], acc[(M0)+2][1], 0, 0, 0); \
    acc[(M0)+2][2] = __builtin_amdgcn_mfma_f32_16x16x32_f16(af[2], bf[2], acc[(M0)+2][2], 0, 0, 0); \
    acc[(M0)+2][3] = __builtin_amdgcn_mfma_f32_16x16x32_f16(af[2], bf[3], acc[(M0)+2][3], 0, 0, 0); \
    acc[(M0)+3][0] = __builtin_amdgcn_mfma_f32_16x16x32_f16(af[3], bf[0], acc[(M0)+3][0], 0, 0, 0); \
    acc[(M0)+3][1] = __builtin_amdgcn_mfma_f32_16x16x32_f16(af[3], bf[1], acc[(M0)+3][1], 0, 0, 0); \
    acc[(M0)+3][2] = __builtin_amdgcn_mfma_f32_16x16x32_f16(af[3], bf[2], acc[(M0)+3][2], 0, 0, 0); \
    acc[(M0)+3][3] = __builtin_amdgcn_mfma_f32_16x16x32_f16(af[3], bf[3], acc[(M0)+3][3], 0, 0, 0); \
    __builtin_amdgcn_s_setprio(0);

    for (int i = 0; i < niter; ++i) {
        const int t0 = 2 * i;
        const int s0 = t0 & 3, s1 = (t0 + 1) & 3;
        const int sA = (t0 + 3) & 3;     // stage target, phases 0-1 (tile t0+3)
        const int sB = s0;               // stage target, phases 2-3 (tile t0+4)
        const bool stg01 = (t0 + 3 < nk);
        const bool stg23 = (t0 + 4 < nk);

        f16x8 bf[4], af[4];

        // ---- phase 0: tile t0, mi 0-3 ----
        {
            BFLOAD(s0);
            LDA4(s0, 0);
            if (stg01) {
                stage16(Ab + aoff0, &As[sA][8 * (size_t)c0]);
                stage16(Ab + aoff1, &As[sA][8 * (size_t)c1]);
            }
            barrier_();
            MFMA16(0);
            barrier_();
        }
        // ---- phase 1: tile t0, mi 4-7; K-tile boundary wait ----
        {
            LDA4(s0, 4);
            if (stg01) {
                stage16(Wb + woff0, &Bs[sA][8 * (size_t)c0]);
                stage16(Wb + woff1, &Bs[sA][8 * (size_t)c1]);
            }
            barrier_();
            MFMA16(4);
            // tile t0+1 must be landed for all waves after this barrier.
            if (i + 1 < niter) vmwait<8>(); else vmwait<0>();
            barrier_();
        }
        aoff0 += KSTEP; aoff1 += KSTEP; woff0 += KSTEP; woff1 += KSTEP;

        // ---- phase 2: tile t0+1, mi 0-3 ----
        {
            BFLOAD(s1);
            LDA4(s1, 0);
            if (stg23) {
                stage16(Ab + aoff0, &As[sB][8 * (size_t)c0]);
                stage16(Ab + aoff1, &As[sB][8 * (size_t)c1]);
            }
            barrier_();
            MFMA16(0);
            barrier_();
        }
        // ---- phase 3: tile t0+1, mi 4-7; iteration boundary wait ----
        {
            LDA4(s1, 4);
            if (stg23) {
                stage16(Wb + woff0, &Bs[sB][8 * (size_t)c0]);
                stage16(Wb + woff1, &Bs[sB][8 * (size_t)c1]);
            }
            barrier_();
            MFMA16(4);
            // tile t0+2 must be landed for all waves after this barrier.
            if (i + 2 < niter)      vmwait<8>();
            else if (i + 1 < niter) vmwait<4>();
            barrier_();
        }
        aoff0 += KSTEP; aoff1 += KSTEP; woff0 += KSTEP; woff1 += KSTEP;
    }
#undef BFLOAD
#undef LDA4
#undef MFMA16

    // epilogue: bias (+relu), store. C/D: col=lane&15, row=(lane>>4)*4+reg.
    const int q = lane >> 4;
    float bcol[4];
    {
        const float* bp = bias + (size_t)b * N + bn * BN + wn;
#pragma unroll
        for (int ni = 0; ni < 4; ++ni) bcol[ni] = bp[ni * 16 + rowl];
    }
#pragma unroll
    for (int mi = 0; mi < 8; ++mi) {
        const int row0 = bm * BM + wm + mi * 16 + q * 4;
#pragma unroll
        for (int r = 0; r < 4; ++r) {
            const size_t ro = (size_t)b * M * N + (size_t)(row0 + r) * N + bn * BN + wn;
#pragma unroll
            for (int ni = 0; ni < 4; ++ni) {
                float v = acc[mi][ni][r] + bcol[ni];
                if (RELU) v = fmaxf(v, 0.f);
                if (OUT_F16)
                    ((_Float16*)Outv)[ro + ni * 16 + rowl] = (_Float16)v;
                else
                    ((float*)Outv)[ro + ni * 16 + rowl] = v;
            }
        }
    }
}

// ---- legacy 2-barrier kernel, mixed f32/f16 operands (fallback path only) ----
__device__ __forceinline__ uint4 load8f32(const char* p) {
    const float4* fp = reinterpret_cast<const float4*>(p);
    float4 f0 = fp[0], f1 = fp[1];
    f16x8 o;
    o[0] = (_Float16)f0.x; o[1] = (_Float16)f0.y;
    o[2] = (_Float16)f0.z; o[3] = (_Float16)f0.w;
    o[4] = (_Float16)f1.x; o[5] = (_Float16)f1.y;
    o[6] = (_Float16)f1.z; o[7] = (_Float16)f1.w;
    return __builtin_bit_cast(uint4, o);
}

template <bool A_F16, bool W_F16, bool RELU, bool OUT_F16>
__global__ __launch_bounds__(256) void gemm_bias_act(
    const void* __restrict__ Av, const void* __restrict__ Wv,
    const float* __restrict__ bias, void* __restrict__ Outv,
    int M, int N, int K) {
    constexpr int BM = 128, BN = 128, BK = 32;
    __shared__ __align__(16) _Float16 As[BM * BK];
    __shared__ __align__(16) _Float16 Bs[BN * BK];

    const int tid  = threadIdx.x;
    const int lane = tid & 63;
    const int rowl = lane & 15;
    const int q8   = (lane >> 4) * 8;
    const int wm   = ((tid >> 6) >> 1) * 64;
    const int wn   = ((tid >> 6) & 1) * 64;
    const int bm = blockIdx.x, bn = blockIdx.y, b = blockIdx.z;

    const int c0 = tid, c1 = tid + 256;
    const int ar0 = c0 >> 2, ak0 = (c0 & 3) * 8;
    const int ar1 = c1 >> 2, ak1 = (c1 & 3) * 8;

    constexpr size_t esA = A_F16 ? 2 : 4;
    constexpr size_t esW = W_F16 ? 2 : 4;
    const char* Abase = (const char*)Av;
    const char* Wbase = (const char*)Wv;

    size_t aoff0 = ((size_t)b * M * K + (size_t)(bm * BM + ar0) * K + ak0) * esA;
    size_t aoff1 = ((size_t)b * M * K + (size_t)(bm * BM + ar1) * K + ak1) * esA;
    size_t woff0 = ((size_t)b * N * K + (size_t)(bn * BN + ar0) * K + ak0) * esW;
    size_t woff1 = ((size_t)b * N * K + (size_t)(bn * BN + ar1) * K + ak1) * esW;

    f32x4 acc[4][4];
#pragma unroll
    for (int mi = 0; mi < 4; ++mi)
#pragma unroll
        for (int ni = 0; ni < 4; ++ni)
            acc[mi][ni] = (f32x4){0.f, 0.f, 0.f, 0.f};

    const int nk = K / BK;
    for (int kk = 0; kk < nk; ++kk) {
        uint4 va0, va1, vw0, vw1;
        if (!A_F16) { va0 = load8f32(Abase + aoff0); va1 = load8f32(Abase + aoff1); }
        if (!W_F16) { vw0 = load8f32(Wbase + woff0); vw1 = load8f32(Wbase + woff1); }
        __syncthreads();
        if (A_F16) {
            stage16(Abase + aoff0, As + 8 * (size_t)c0);
            stage16(Abase + aoff1, As + 8 * (size_t)c1);
        } else {
            *(uint4*)(As + ar0 * BK + ak0) = va0;
            *(uint4*)(As + ar1 * BK + ak1) = va1;
        }
        if (W_F16) {
            stage16(Wbase + woff0, Bs + 8 * (size_t)c0);
            stage16(Wbase + woff1, Bs + 8 * (size_t)c1);
        } else {
            *(uint4*)(Bs + ar0 * BK + ak0) = vw0;
            *(uint4*)(Bs + ar1 * BK + ak1) = vw1;
        }
        aoff0 += BK * esA; aoff1 += BK * esA;
        woff0 += BK * esW; woff1 += BK * esW;
        __syncthreads();

        f16x8 af[4], bf[4];
#pragma unroll
        for (int i = 0; i < 4; ++i)
            af[i] = *(const f16x8*)(As + (wm + i * 16 + rowl) * BK + q8);
#pragma unroll
        for (int i = 0; i < 4; ++i)
            bf[i] = *(const f16x8*)(Bs + (wn + i * 16 + rowl) * BK + q8);
#pragma unroll
        for (int mi = 0; mi < 4; ++mi)
#pragma unroll
            for (int ni = 0; ni < 4; ++ni)
                acc[mi][ni] = __builtin_amdgcn_mfma_f32_16x16x32_f16(
                    af[mi], bf[ni], acc[mi][ni], 0, 0, 0);
    }

    const int q = lane >> 4;
    float bcol[4];
    {
        const float* bp = bias + (size_t)b * N + bn * BN + wn;
#pragma unroll
        for (int ni = 0; ni < 4; ++ni) bcol[ni] = bp[ni * 16 + rowl];
    }
#pragma unroll
    for (int mi = 0; mi < 4; ++mi) {
        const int row0 = bm * BM + wm + mi * 16 + q * 4;
#pragma unroll
        for (int r = 0; r < 4; ++r) {
            const size_t ro = (size_t)b * M * N + (size_t)(row0 + r) * N + bn * BN + wn;
#pragma unroll
            for (int ni = 0; ni < 4; ++ni) {
                float v = acc[mi][ni][r] + bcol[ni];
                if (RELU) v = fmaxf(v, 0.f);
                if (OUT_F16)
                    ((_Float16*)Outv)[ro + ni * 16 + rowl] = (_Float16)v;
                else
                    ((float*)Outv)[ro + ni * 16 + rowl] = v;
            }
        }
    }
}

extern "C" void kernel_launch(void* const* d_in, const int* in_sizes, int n_in,
                              void* d_out, int out_size, void* d_ws, size_t ws_size,
                              hipStream_t stream) {
    const int B = 8, S = 4096, DI = 512, DH = 1024, DO = 512;
    const float* query = (const float*)d_in[0];
    const float* W0    = (const float*)d_in[1];
    const float* b0    = (const float*)d_in[2];
    const float* W1    = (const float*)d_in[3];
    const float* b1    = (const float*)d_in[4];
    const float* W2    = (const float*)d_in[5];
    const float* b2    = (const float*)d_in[6];

    char* ws = (char*)d_ws;
    const size_t nH  = (size_t)B * S * DH;   // 33.5M
    const size_t nQ  = (size_t)B * S * DI;   // 16.8M
    const size_t nW0 = (size_t)B * DH * DI;  // 4.2M
    const size_t nW1 = (size_t)B * DH * DH;  // 8.4M
    const size_t nW2 = (size_t)B * DO * DH;  // 4.2M

    _Float16* h0 = (_Float16*)ws;             // 64 MiB
    _Float16* h1 = (_Float16*)(ws + nH * 2);  // 64 MiB
    const size_t off_casts = nH * 4;
    const size_t full_need = off_casts + (nQ + nW0 + nW1 + nW2) * 2;  // 192 MiB

    if (ws_size >= full_need) {
        _Float16* qf  = (_Float16*)(ws + off_casts);
        _Float16* w0f = qf + nQ;
        _Float16* w1f = w0f + nW0;
        _Float16* w2f = w1f + nW1;
        cast_all<<<dim3(2048), dim3(256), 0, stream>>>(
            query, qf, (int)(nQ / 4), W0, w0f, (int)(nW0 / 4),
            W1, w1f, (int)(nW1 / 4), W2, w2f, (int)(nW2 / 4));
        const dim3 blk(512);
        const dim3 g0(S / 256, DH / 256, B);
        const dim3 g2(S / 256, DO / 256, B);
        gemm_pipe4<true,  true ><<<g0, blk, 0, stream>>>(qf, w0f, b0, h0, S, DH, DI);
        gemm_pipe4<true,  true ><<<g0, blk, 0, stream>>>(h0, w1f, b1, h1, S, DH, DH);
        gemm_pipe4<false, false><<<g2, blk, 0, stream>>>(h1, w2f, b2, d_out, S, DO, DH);
    } else {
        const dim3 blk(256);
        const dim3 g0(S / 128, DH / 128, B);
        const dim3 g2(S / 128, DO / 128, B);
        gemm_bias_act<false, false, true,  true ><<<g0, blk, 0, stream>>>(query, W0, b0, h0, S, DH, DI);
        gemm_bias_act<true,  false, true,  true ><<<g0, blk, 0, stream>>>(h0, W1, b1, h1, S, DH, DH);
        gemm_bias_act<true,  false, false, false><<<g2, blk, 0, stream>>>(h1, W2, b2, d_out, S, DO, DH);
    }
}

// Round 4
// 328.625 us; speedup vs baseline: 1.1145x; 1.0254x over previous
//
#include <hip/hip_runtime.h>

// LongTermMemoryMLP: 3 batched NT-GEMMs with per-batch weights.
//   h0 = relu(q  @ W0^T + b0)   [8,4096,512]x[8,1024,512]^T
//   h1 = relu(h0 @ W1^T + b1)   [8,4096,1024]x[8,1024,1024]^T
//   out =      h1 @ W2^T + b2   [8,4096,1024]x[8,512,1024]^T  (fp32 out)
// f16 MFMA, fp32 accumulate.
// Round 7: cross-phase register prefetch. Each phase now issues the NEXT
// phase's ds_reads (into the alternate fragment register set) before running
// this phase's MFMA cluster, so the LDS pipe overlaps the matrix pipe
// (counted lgkmcnt instead of same-phase dependency). One barrier per phase
// (4 per 2 K-tiles, was 8). Staging remapped Q0:A(t+3) Q1:W(t+3) Q2:W(t+4)
// Q3:A(t+4) so no phase stages a buffer it reads. vmcnt(6) at Q1/Q3 entry.
// Keeps R5's conflict-free both-sides XOR swizzle (bank conflicts = 0).

typedef _Float16 f16x8 __attribute__((ext_vector_type(8)));
typedef _Float16 f16x4 __attribute__((ext_vector_type(4)));
typedef float    f32x4 __attribute__((ext_vector_type(4)));

// async global->LDS DMA, 16B per lane; LDS dest = wave-uniform base + lane*16.
__device__ __forceinline__ void stage16(const void* g, void* l) {
    __builtin_amdgcn_global_load_lds(
        (const __attribute__((address_space(1))) unsigned int*)g,
        (__attribute__((address_space(3))) unsigned int*)l,
        16, 0, 0);
}

template <int CNT> __device__ __forceinline__ void vmwait() {
    if constexpr (CNT == 8)      asm volatile("s_waitcnt vmcnt(8)" ::: "memory");
    else if constexpr (CNT == 6) asm volatile("s_waitcnt vmcnt(6)" ::: "memory");
    else if constexpr (CNT == 4) asm volatile("s_waitcnt vmcnt(4)" ::: "memory");
    else                         asm volatile("s_waitcnt vmcnt(0)" ::: "memory");
}
__device__ __forceinline__ void barrier_() {
    asm volatile("s_barrier" ::: "memory");
}

// ---- fp32 -> f16 casts, all four arrays in one launch ----
__device__ __forceinline__ void cast_seg(const float* __restrict__ s,
                                         _Float16* __restrict__ d, int n4) {
    const int stride = gridDim.x * 256;
    for (int i = blockIdx.x * 256 + threadIdx.x; i < n4; i += stride) {
        float4 f = reinterpret_cast<const float4*>(s)[i];
        f16x4 o;
        o[0] = (_Float16)f.x; o[1] = (_Float16)f.y;
        o[2] = (_Float16)f.z; o[3] = (_Float16)f.w;
        reinterpret_cast<f16x4*>(d)[i] = o;
    }
}

__global__ __launch_bounds__(256) void cast_all(
    const float* s0, _Float16* d0, int n0,
    const float* s1, _Float16* d1, int n1,
    const float* s2, _Float16* d2, int n2,
    const float* s3, _Float16* d3, int n3) {
    cast_seg(s0, d0, n0);
    cast_seg(s1, d1, n1);
    cast_seg(s2, d2, n2);
    cast_seg(s3, d3, n3);
}

// ---- register-pipelined all-f16 GEMM: C[b,m,n] = sum_k A[b,m,k]*W[b,n,k]+b
// 256x256 tile, BK=32, 8 waves (2Mx4N), each wave 8x4 x mfma_f32_16x16x32_f16.
// LDS ring of 4 K-tiles (128 KiB). 4 phases per 2 K-tiles, ONE barrier per
// phase; fragment registers double-buffered across phases:
//   Qp: {barrier | ds_reads for Q(p+1) -> alt reg set | stage16 | MFMA16}
// LDS 16B k-chunk XOR-swizzled by (row>>1)&3 on BOTH sides (global source for
// the linear DMA dest; same XOR on ds_read) -> conflict-free b128 reads.
template <bool RELU, bool OUT_F16>
__global__ __launch_bounds__(512, 2) void gemm_rpipe(
    const _Float16* __restrict__ A, const _Float16* __restrict__ W,
    const float* __restrict__ bias, void* __restrict__ Outv,
    int M, int N, int K) {
    constexpr int BM = 256, BN = 256, BK = 32;
    constexpr int DEPTH = 4;                       // K-tiles resident in LDS
    __shared__ __align__(16) _Float16 As[DEPTH][BM * BK];   // 4 x 16 KiB
    __shared__ __align__(16) _Float16 Bs[DEPTH][BN * BK];   // 4 x 16 KiB

    const int tid  = threadIdx.x;
    const int lane = tid & 63;
    const int rowl = lane & 15;
    // swizzled k-chunk for fragment reads: q' = (lane>>4) ^ ((row>>1)&3);
    // row = 16*m + rowl  =>  (row>>1)&3 == (rowl>>1)&3  (per-thread constant).
    const int qswz = (((lane >> 4) ^ ((rowl >> 1) & 3)) * 8);
    const int w    = tid >> 6;            // wave 0..7
    const int wm   = (w >> 2) * 128;      // 2 waves along M
    const int wn   = (w & 3) * 64;        // 4 waves along N

    const int bm = blockIdx.x, bn = blockIdx.y, b = blockIdx.z;

    // chunk c (0..1023, 8 f16 = 16 B each): LDS dest f16-offset 8*c (linear —
    // DMA constraint); holds global (row=c>>2, k-chunk (c&3)^((row>>1)&3)).
    const int c0 = tid, c1 = tid + 512;
    const int ar0 = c0 >> 2, ar1 = c1 >> 2;
    const int ak0 = (((c0 & 3) ^ ((ar0 >> 1) & 3)) * 8);
    const int ak1 = (((c1 & 3) ^ ((ar1 >> 1) & 3)) * 8);

    const char* Ab = (const char*)(A + (size_t)b * M * K + (size_t)(bm * BM) * K);
    const char* Wb = (const char*)(W + (size_t)b * N * K + (size_t)(bn * BN) * K);
    size_t aoff0 = ((size_t)ar0 * K + ak0) * 2;
    size_t aoff1 = ((size_t)ar1 * K + ak1) * 2;
    size_t woff0 = ((size_t)ar0 * K + ak0) * 2;
    size_t woff1 = ((size_t)ar1 * K + ak1) * 2;
    constexpr size_t KSTEP = (size_t)BK * 2;      // byte advance per K-tile

    f32x4 acc[8][4];
#pragma unroll
    for (int mi = 0; mi < 8; ++mi)
#pragma unroll
        for (int ni = 0; ni < 4; ++ni)
            acc[mi][ni] = (f32x4){0.f, 0.f, 0.f, 0.f};

    const int nk = K / BK;          // even, >= 16 (K in {512,1024})
    const int niter = nk / 2;

    // prologue: stage tiles 0..2 (12 DMA instrs/wave); wait tile 0 (allow
    // tiles 1,2 = 8 instrs in flight), then preload tile-0 fragments.
#pragma unroll
    for (int p = 0; p < DEPTH - 1; ++p) {
        stage16(Ab + aoff0, &As[p][8 * (size_t)c0]);
        stage16(Ab + aoff1, &As[p][8 * (size_t)c1]);
        stage16(Wb + woff0, &Bs[p][8 * (size_t)c0]);
        stage16(Wb + woff1, &Bs[p][8 * (size_t)c1]);
        aoff0 += KSTEP; aoff1 += KSTEP; woff0 += KSTEP; woff1 += KSTEP;
    }
    vmwait<8>();
    barrier_();

    f16x8 afA[4], afB[4], bfA[4], bfB[4];

#define LDAF(DST, SS, M0)                                                        \
    DST[0] = *(const f16x8*)(&As[SS][(wm + ((M0)+0)*16 + rowl) * BK + qswz]);    \
    DST[1] = *(const f16x8*)(&As[SS][(wm + ((M0)+1)*16 + rowl) * BK + qswz]);    \
    DST[2] = *(const f16x8*)(&As[SS][(wm + ((M0)+2)*16 + rowl) * BK + qswz]);    \
    DST[3] = *(const f16x8*)(&As[SS][(wm + ((M0)+3)*16 + rowl) * BK + qswz]);

#define LDBF(DST, SS)                                                            \
    DST[0] = *(const f16x8*)(&Bs[SS][(wn +  0 + rowl) * BK + qswz]);             \
    DST[1] = *(const f16x8*)(&Bs[SS][(wn + 16 + rowl) * BK + qswz]);             \
    DST[2] = *(const f16x8*)(&Bs[SS][(wn + 32 + rowl) * BK + qswz]);             \
    DST[3] = *(const f16x8*)(&Bs[SS][(wn + 48 + rowl) * BK + qswz]);

#define MFMA16(AF, BF, M0)                                                       \
    __builtin_amdgcn_s_setprio(1);                                               \
    acc[(M0)+0][0] = __builtin_amdgcn_mfma_f32_16x16x32_f16(AF[0], BF[0], acc[(M0)+0][0], 0, 0, 0); \
    acc[(M0)+0][1] = __builtin_amdgcn_mfma_f32_16x16x32_f16(AF[0], BF[1], acc[(M0)+0][1], 0, 0, 0); \
    acc[(M0)+0][2] = __builtin_amdgcn_mfma_f32_16x16x32_f16(AF[0], BF[2], acc[(M0)+0][2], 0, 0, 0); \
    acc[(M0)+0][3] = __builtin_amdgcn_mfma_f32_16x16x32_f16(AF[0], BF[3], acc[(M0)+0][3], 0, 0, 0); \
    acc[(M0)+1][0] = __builtin_amdgcn_mfma_f32_16x16x32_f16(AF[1], BF[0], acc[(M0)+1][0], 0, 0, 0); \
    acc[(M0)+1][1] = __builtin_amdgcn_mfma_f32_16x16x32_f16(AF[1], BF[1], acc[(M0)+1][1], 0, 0, 0); \
    acc[(M0)+1][2] = __builtin_amdgcn_mfma_f32_16x16x32_f16(AF[1], BF[2], acc[(M0)+1][2], 0, 0, 0); \
    acc[(M0)+1][3] = __builtin_amdgcn_mfma_f32_16x16x32_f16(AF[1], BF[3], acc[(M0)+1][3], 0, 0, 0); \
    acc[(M0)+2][0] = __builtin_amdgcn_mfma_f32_16x16x32_f16(AF[2], BF[0], acc[(M0)+2][0], 0, 0, 0); \
    acc[(M0)+2][1] = __builtin_amdgcn_mfma_f32_16x16x32_f16(AF[2], BF[1], acc[(M0)+2][1], 0, 0, 0); \
    acc[(M0)+2][2] = __builtin_amdgcn_mfma_f32_16x16x32_f16(AF[2], BF[2], acc[(M0)+2][2], 0, 0, 0); \
    acc[(M0)+2][3] = __builtin_amdgcn_mfma_f32_16x16x32_f16(AF[2], BF[3], acc[(M0)+2][3], 0, 0, 0); \
    acc[(M0)+3][0] = __builtin_amdgcn_mfma_f32_16x16x32_f16(AF[3], BF[0], acc[(M0)+3][0], 0, 0, 0); \
    acc[(M0)+3][1] = __builtin_amdgcn_mfma_f32_16x16x32_f16(AF[3], BF[1], acc[(M0)+3][1], 0, 0, 0); \
    acc[(M0)+3][2] = __builtin_amdgcn_mfma_f32_16x16x32_f16(AF[3], BF[2], acc[(M0)+3][2], 0, 0, 0); \
    acc[(M0)+3][3] = __builtin_amdgcn_mfma_f32_16x16x32_f16(AF[3], BF[3], acc[(M0)+3][3], 0, 0, 0); \
    __builtin_amdgcn_s_setprio(0);

    // preload tile 0 fragments: bfA = Bs[0], afA = As[0] quad0.
    LDBF(bfA, 0);
    LDAF(afA, 0, 0);

    for (int i = 0; i < niter; ++i) {
        const int t0 = 2 * i;
        const int s0 = t0 & 3, s1 = (t0 + 1) & 3, s2 = (t0 + 2) & 3;
        const int sA = (t0 + 3) & 3;     // odd tile t0+3: A in Q0, W in Q1
        const int sB = s0;               // even tile t0+4: W in Q2, A in Q3
        const bool stgO = (t0 + 3 < nk);
        const bool stgE = (t0 + 4 < nk);
        const bool last = (i + 1 == niter);

        // ---- Q0: MFMA (s0, mi0-3); prefetch afB <- As[s0] quad1 ----
        barrier_();
        LDAF(afB, s0, 4);
        if (stgO) {
            stage16(Ab + aoff0, &As[sA][8 * (size_t)c0]);
            stage16(Ab + aoff1, &As[sA][8 * (size_t)c1]);
        }
        aoff0 += KSTEP; aoff1 += KSTEP;           // A ptr -> tile t0+4
        MFMA16(afA, bfA, 0);
        if (!last) vmwait<6>(); else vmwait<0>(); // tile t0+1 landed

        // ---- Q1: MFMA (s0, mi4-7); prefetch bfB <- Bs[s1], afA <- As[s1] q0
        barrier_();
        LDBF(bfB, s1);
        LDAF(afA, s1, 0);
        if (stgO) {
            stage16(Wb + woff0, &Bs[sA][8 * (size_t)c0]);
            stage16(Wb + woff1, &Bs[sA][8 * (size_t)c1]);
        }
        woff0 += KSTEP; woff1 += KSTEP;           // W ptr -> tile t0+4
        MFMA16(afB, bfA, 4);

        // ---- Q2: MFMA (s1, mi0-3); prefetch afB <- As[s1] quad1 ----
        barrier_();
        LDAF(afB, s1, 4);
        if (stgE) {
            stage16(Wb + woff0, &Bs[sB][8 * (size_t)c0]);
            stage16(Wb + woff1, &Bs[sB][8 * (size_t)c1]);
        }
        woff0 += KSTEP; woff1 += KSTEP;           // W ptr -> tile t0+5
        MFMA16(afA, bfB, 0);
        if (i + 2 < niter)      vmwait<6>();      // tile t0+2 landed
        else if (i + 1 < niter) vmwait<4>();

        // ---- Q3: MFMA (s1, mi4-7); prefetch bfA/afA <- tile s2 (next s0) --
        barrier_();
        if (!last) {
            LDBF(bfA, s2);
            LDAF(afA, s2, 0);
        }
        if (stgE) {
            stage16(Ab + aoff0, &As[sB][8 * (size_t)c0]);
            stage16(Ab + aoff1, &As[sB][8 * (size_t)c1]);
        }
        aoff0 += KSTEP; aoff1 += KSTEP;           // A ptr -> tile t0+5
        MFMA16(afB, bfB, 4);
    }
#undef LDAF
#undef LDBF
#undef MFMA16

    // epilogue: bias (+relu), store. C/D: col=lane&15, row=(lane>>4)*4+reg.
    const int q = lane >> 4;
    float bcol[4];
    {
        const float* bp = bias + (size_t)b * N + bn * BN + wn;
#pragma unroll
        for (int ni = 0; ni < 4; ++ni) bcol[ni] = bp[ni * 16 + rowl];
    }
#pragma unroll
    for (int mi = 0; mi < 8; ++mi) {
        const int row0 = bm * BM + wm + mi * 16 + q * 4;
#pragma unroll
        for (int r = 0; r < 4; ++r) {
            const size_t ro = (size_t)b * M * N + (size_t)(row0 + r) * N + bn * BN + wn;
#pragma unroll
            for (int ni = 0; ni < 4; ++ni) {
                float v = acc[mi][ni][r] + bcol[ni];
                if (RELU) v = fmaxf(v, 0.f);
                if (OUT_F16)
                    ((_Float16*)Outv)[ro + ni * 16 + rowl] = (_Float16)v;
                else
                    ((float*)Outv)[ro + ni * 16 + rowl] = v;
            }
        }
    }
}

// ---- legacy 2-barrier kernel, mixed f32/f16 operands (fallback path only) ----
__device__ __forceinline__ uint4 load8f32(const char* p) {
    const float4* fp = reinterpret_cast<const float4*>(p);
    float4 f0 = fp[0], f1 = fp[1];
    f16x8 o;
    o[0] = (_Float16)f0.x; o[1] = (_Float16)f0.y;
    o[2] = (_Float16)f0.z; o[3] = (_Float16)f0.w;
    o[4] = (_Float16)f1.x; o[5] = (_Float16)f1.y;
    o[6] = (_Float16)f1.z; o[7] = (_Float16)f1.w;
    return __builtin_bit_cast(uint4, o);
}

template <bool A_F16, bool W_F16, bool RELU, bool OUT_F16>
__global__ __launch_bounds__(256) void gemm_bias_act(
    const void* __restrict__ Av, const void* __restrict__ Wv,
    const float* __restrict__ bias, void* __restrict__ Outv,
    int M, int N, int K) {
    constexpr int BM = 128, BN = 128, BK = 32;
    __shared__ __align__(16) _Float16 As[BM * BK];
    __shared__ __align__(16) _Float16 Bs[BN * BK];

    const int tid  = threadIdx.x;
    const int lane = tid & 63;
    const int rowl = lane & 15;
    const int q8   = (lane >> 4) * 8;
    const int wm   = ((tid >> 6) >> 1) * 64;
    const int wn   = ((tid >> 6) & 1) * 64;
    const int bm = blockIdx.x, bn = blockIdx.y, b = blockIdx.z;

    const int c0 = tid, c1 = tid + 256;
    const int ar0 = c0 >> 2, ak0 = (c0 & 3) * 8;
    const int ar1 = c1 >> 2, ak1 = (c1 & 3) * 8;

    constexpr size_t esA = A_F16 ? 2 : 4;
    constexpr size_t esW = W_F16 ? 2 : 4;
    const char* Abase = (const char*)Av;
    const char* Wbase = (const char*)Wv;

    size_t aoff0 = ((size_t)b * M * K + (size_t)(bm * BM + ar0) * K + ak0) * esA;
    size_t aoff1 = ((size_t)b * M * K + (size_t)(bm * BM + ar1) * K + ak1) * esA;
    size_t woff0 = ((size_t)b * N * K + (size_t)(bn * BN + ar0) * K + ak0) * esW;
    size_t woff1 = ((size_t)b * N * K + (size_t)(bn * BN + ar1) * K + ak1) * esW;

    f32x4 acc[4][4];
#pragma unroll
    for (int mi = 0; mi < 4; ++mi)
#pragma unroll
        for (int ni = 0; ni < 4; ++ni)
            acc[mi][ni] = (f32x4){0.f, 0.f, 0.f, 0.f};

    const int nk = K / BK;
    for (int kk = 0; kk < nk; ++kk) {
        uint4 va0, va1, vw0, vw1;
        if (!A_F16) { va0 = load8f32(Abase + aoff0); va1 = load8f32(Abase + aoff1); }
        if (!W_F16) { vw0 = load8f32(Wbase + woff0); vw1 = load8f32(Wbase + woff1); }
        __syncthreads();
        if (A_F16) {
            stage16(Abase + aoff0, As + 8 * (size_t)c0);
            stage16(Abase + aoff1, As + 8 * (size_t)c1);
        } else {
            *(uint4*)(As + ar0 * BK + ak0) = va0;
            *(uint4*)(As + ar1 * BK + ak1) = va1;
        }
        if (W_F16) {
            stage16(Wbase + woff0, Bs + 8 * (size_t)c0);
            stage16(Wbase + woff1, Bs + 8 * (size_t)c1);
        } else {
            *(uint4*)(Bs + ar0 * BK + ak0) = vw0;
            *(uint4*)(Bs + ar1 * BK + ak1) = vw1;
        }
        aoff0 += BK * esA; aoff1 += BK * esA;
        woff0 += BK * esW; woff1 += BK * esW;
        __syncthreads();

        f16x8 af[4], bf[4];
#pragma unroll
        for (int i = 0; i < 4; ++i)
            af[i] = *(const f16x8*)(As + (wm + i * 16 + rowl) * BK + q8);
#pragma unroll
        for (int i = 0; i < 4; ++i)
            bf[i] = *(const f16x8*)(Bs + (wn + i * 16 + rowl) * BK + q8);
#pragma unroll
        for (int mi = 0; mi < 4; ++mi)
#pragma unroll
            for (int ni = 0; ni < 4; ++ni)
                acc[mi][ni] = __builtin_amdgcn_mfma_f32_16x16x32_f16(
                    af[mi], bf[ni], acc[mi][ni], 0, 0, 0);
    }

    const int q = lane >> 4;
    float bcol[4];
    {
        const float* bp = bias + (size_t)b * N + bn * BN + wn;
#pragma unroll
        for (int ni = 0; ni < 4; ++ni) bcol[ni] = bp[ni * 16 + rowl];
    }
#pragma unroll
    for (int mi = 0; mi < 4; ++mi) {
        const int row0 = bm * BM + wm + mi * 16 + q * 4;
#pragma unroll
        for (int r = 0; r < 4; ++r) {
            const size_t ro = (size_t)b * M * N + (size_t)(row0 + r) * N + bn * BN + wn;
#pragma unroll
            for (int ni = 0; ni < 4; ++ni) {
                float v = acc[mi][ni][r] + bcol[ni];
                if (RELU) v = fmaxf(v, 0.f);
                if (OUT_F16)
                    ((_Float16*)Outv)[ro + ni * 16 + rowl] = (_Float16)v;
                else
                    ((float*)Outv)[ro + ni * 16 + rowl] = v;
            }
        }
    }
}

extern "C" void kernel_launch(void* const* d_in, const int* in_sizes, int n_in,
                              void* d_out, int out_size, void* d_ws, size_t ws_size,
                              hipStream_t stream) {
    const int B = 8, S = 4096, DI = 512, DH = 1024, DO = 512;
    const float* query = (const float*)d_in[0];
    const float* W0    = (const float*)d_in[1];
    const float* b0    = (const float*)d_in[2];
    const float* W1    = (const float*)d_in[3];
    const float* b1    = (const float*)d_in[4];
    const float* W2    = (const float*)d_in[5];
    const float* b2    = (const float*)d_in[6];

    char* ws = (char*)d_ws;
    const size_t nH  = (size_t)B * S * DH;   // 33.5M
    const size_t nQ  = (size_t)B * S * DI;   // 16.8M
    const size_t nW0 = (size_t)B * DH * DI;  // 4.2M
    const size_t nW1 = (size_t)B * DH * DH;  // 8.4M
    const size_t nW2 = (size_t)B * DO * DH;  // 4.2M

    _Float16* h0 = (_Float16*)ws;             // 64 MiB
    _Float16* h1 = (_Float16*)(ws + nH * 2);  // 64 MiB
    const size_t off_casts = nH * 4;
    const size_t full_need = off_casts + (nQ + nW0 + nW1 + nW2) * 2;  // 192 MiB

    if (ws_size >= full_need) {
        _Float16* qf  = (_Float16*)(ws + off_casts);
        _Float16* w0f = qf + nQ;
        _Float16* w1f = w0f + nW0;
        _Float16* w2f = w1f + nW1;
        cast_all<<<dim3(2048), dim3(256), 0, stream>>>(
            query, qf, (int)(nQ / 4), W0, w0f, (int)(nW0 / 4),
            W1, w1f, (int)(nW1 / 4), W2, w2f, (int)(nW2 / 4));
        const dim3 blk(512);
        const dim3 g0(S / 256, DH / 256, B);
        const dim3 g2(S / 256, DO / 256, B);
        gemm_rpipe<true,  true ><<<g0, blk, 0, stream>>>(qf, w0f, b0, h0, S, DH, DI);
        gemm_rpipe<true,  true ><<<g0, blk, 0, stream>>>(h0, w1f, b1, h1, S, DH, DH);
        gemm_rpipe<false, false><<<g2, blk, 0, stream>>>(h1, w2f, b2, d_out, S, DO, DH);
    } else {
        const dim3 blk(256);
        const dim3 g0(S / 128, DH / 128, B);
        const dim3 g2(S / 128, DO / 128, B);
        gemm_bias_act<false, false, true,  true ><<<g0, blk, 0, stream>>>(query, W0, b0, h0, S, DH, DI);
        gemm_bias_act<true,  false, true,  true ><<<g0, blk, 0, stream>>>(h0, W1, b1, h1, S, DH, DH);
        gemm_bias_act<true,  false, false, false><<<g2, blk, 0, stream>>>(h1, W2, b2, d_out, S, DO, DH);
    }
}